// Round 4
// baseline (56.389 us; speedup 1.0000x reference)
//
#include <hip/hip_runtime.h>
#include <stdint.h>

// Problem constants
#define NINq   512
#define DIMq   64
#define NHEADq 8
#define Bq     2
#define Nq     2048
#define MTOT   4096          // B*N rows
#define CHELEM 131072        // 2048*64 elements per chunk

typedef __attribute__((ext_vector_type(4))) float   f32x4;
typedef __attribute__((ext_vector_type(8))) short   bh8;     // 8 bf16 in 4 VGPRs
typedef __attribute__((ext_vector_type(4))) unsigned short u16x4;
typedef unsigned short u16;

__device__ inline u16 f2bf(float f) {
    union { float f; uint32_t u; } v; v.f = f;
    uint32_t u = v.u;
    u += 0x7FFF + ((u >> 16) & 1);         // RNE
    return (u16)(u >> 16);
}

__device__ inline void gload_lds16(const u16* g, u16* l) {
    __builtin_amdgcn_global_load_lds(
        (const __attribute__((address_space(1))) uint32_t*)g,
        (__attribute__((address_space(3)))       uint32_t*)l,
        16, 0, 0);
}

// ---------------- K0: convert x, Wq, Wk, Wv to bf16 ----------------
__global__ __launch_bounds__(256) void k0_convert(
        const float* __restrict__ x,
        const float* __restrict__ Wq,
        const float* __restrict__ Wk,
        const float* __restrict__ Wv,
        u16* __restrict__ xb, u16* __restrict__ Wb) {
    int idx = blockIdx.x * 256 + threadIdx.x;   // float4 index, 720896 total
    const float4* src; u16* dst; int off;
    if (idx < 524288) { src = (const float4*)x; dst = xb; off = idx; }
    else {
        int j = idx - 524288;
        int w = j >> 16;                        // 65536 float4 per W
        off = j & 65535;
        src = (const float4*)(w == 0 ? Wq : (w == 1 ? Wk : Wv));
        dst = Wb + w * (512 * 512);
    }
    float4 f = src[off];
    u16x4 o;
    o[0] = f2bf(f.x); o[1] = f2bf(f.y); o[2] = f2bf(f.z); o[3] = f2bf(f.w);
    *(u16x4*)(dst + off * 4) = o;
}

// ---------------- K1: QKV projection GEMM ----------------
// C[m,n] = sum_k xb[m,k] * W[n,k] + bias[n]   (gemm_bt), 128x128 tile, BK=64,
// T3-min double-buffered (stage next || compute cur, one sync per K-step).
// Q (w==0): stored straight [4096][512].
// K,V (w==1,2): stored TRANSPOSED per chunk: Kt2[c][d][nh][m8] (layout verified R3).
__global__ __launch_bounds__(256) void k1_qkv(
        const u16* __restrict__ xb, const u16* __restrict__ Wb,
        const float* __restrict__ bq, const float* __restrict__ bk,
        const float* __restrict__ bv,
        u16* __restrict__ Qb, u16* __restrict__ Kb, u16* __restrict__ Vb) {
    __shared__ u16 smem[32768];                 // dbuf A/B (64KB); epilogue tile aliases
    const int tid  = threadIdx.x;
    const int lane = tid & 63, wid = tid >> 6;
    const int wrow = wid >> 1, wcol = wid & 1;
    // XCD swizzle: 384 blocks, 8 XCDs, 48 consecutive per XCD
    const int flat = blockIdx.x;
    const int swz  = (flat & 7) * 48 + (flat >> 3);
    const int mb = swz / 12, nb = swz % 12;
    const int w    = nb >> 2;
    const int nloc = (nb & 3) * 128;
    const u16*   W    = Wb + w * (512 * 512);
    const float* bias = (w == 0) ? bq : ((w == 1) ? bk : bv);
    u16*         out  = (w == 0) ? Qb : ((w == 1) ? Kb : Vb);
    const int m0 = mb * 128;

    f32x4 acc[4][4] = {};
    const int srow = tid >> 3;
    const int scol = (tid & 7) * 8;

    auto stage = [&](int kb, int b) {
        const int k0 = kb * 64;
        u16* bA = smem + b * 16384;
        u16* bB = bA + 8192;
#pragma unroll
        for (int it = 0; it < 4; ++it) {
            int r = it * 32 + srow;
            gload_lds16(xb + (size_t)(m0 + r) * 512 + k0 + scol,   bA + r * 64 + scol);
            gload_lds16(W  + (size_t)(nloc + r) * 512 + k0 + scol, bB + r * 64 + scol);
        }
    };
    auto compute = [&](int b) {
        const u16* bA = smem + b * 16384;
        const u16* bB = bA + 8192;
#pragma unroll
        for (int ks = 0; ks < 2; ++ks) {
            const int kk = ks * 32 + (lane >> 4) * 8;
            bh8 a[4], bfr[4];
#pragma unroll
            for (int i = 0; i < 4; ++i) {
                a[i]   = *(const bh8*)&bA[(wrow * 64 + i * 16 + (lane & 15)) * 64 + kk];
                bfr[i] = *(const bh8*)&bB[(wcol * 64 + i * 16 + (lane & 15)) * 64 + kk];
            }
#pragma unroll
            for (int i = 0; i < 4; ++i)
#pragma unroll
                for (int j = 0; j < 4; ++j)
                    acc[i][j] = __builtin_amdgcn_mfma_f32_16x16x32_bf16(a[i], bfr[j], acc[i][j], 0, 0, 0);
        }
    };

    stage(0, 0);
    __syncthreads();
    for (int kb = 0; kb < 8; ++kb) {
        if (kb < 7) stage(kb + 1, (kb + 1) & 1);
        compute(kb & 1);
        __syncthreads();                       // drains vmcnt(0)+lgkmcnt(0) then barrier
    }

    if (w == 0) {
        // straight store (Q)
#pragma unroll
        for (int i = 0; i < 4; ++i) {
            const int row_base = m0 + wrow * 64 + i * 16 + ((lane >> 4) * 4);
#pragma unroll
            for (int j = 0; j < 4; ++j) {
                const int col = nloc + wcol * 64 + j * 16 + (lane & 15);
                const float bv_ = bias[col];
#pragma unroll
                for (int r = 0; r < 4; ++r)
                    out[(size_t)(row_base + r) * 512 + col] = f2bf(acc[i][j][r] + bv_);
            }
        }
    } else {
        // transposed store (K, V) via padded LDS tile
        u16 (*tile)[130] = (u16(*)[130])smem;
#pragma unroll
        for (int i = 0; i < 4; ++i) {
            const int mrow = wrow * 64 + i * 16 + ((lane >> 4) * 4);
#pragma unroll
            for (int j = 0; j < 4; ++j) {
                const int ncol = wcol * 64 + j * 16 + (lane & 15);
                const float bv_ = bias[nloc + ncol];
#pragma unroll
                for (int r = 0; r < 4; ++r)
                    tile[mrow + r][ncol] = f2bf(acc[i][j][r] + bv_);
            }
        }
        __syncthreads();
        const int c = mb >> 1;
        const int mbase = (mb & 1) * 128;      // m0 & 255
        const int a2 = (nb & 3) * 2;           // nh base
        u16* dstc = out + (size_t)c * CHELEM;
        const int eh   = (tid >> 4) & 1;
        const int mseg = (tid & 15) * 8;
        const int dhi  = tid >> 5;
#pragma unroll
        for (int db = 0; db < 8; ++db) {
            const int d = db * 8 + dhi;
            u16 tmp[8];
#pragma unroll
            for (int k = 0; k < 8; ++k)
                tmp[k] = tile[mseg + k][eh * 64 + d];
            const size_t off = (size_t)d * 2048 + (a2 + eh) * 256 + mbase + mseg;
            *(u16x4*)&dstc[off]     = *(u16x4*)&tmp[0];
            *(u16x4*)&dstc[off + 4] = *(u16x4*)&tmp[4];
        }
    }
}

// ---------------- K2: Pb[c][d][e] = scale * sum_k Vt2[c][d][k] * Kt2[c][e][k] ----------------
// 16 blocks (1/chunk) x 256 thr. Wave w owns K-slice [w*512, w*512+512):
// frags loaded DIRECTLY from global (k-contiguous rows, coalesced, L2-resident),
// no barriers in main loop; one LDS tree-reduction at the end.
__global__ __launch_bounds__(256) void k2_pmat(
        const u16* __restrict__ Kt2, const u16* __restrict__ Vt2,
        u16* __restrict__ Pb) {
    __shared__ float red[4][4096];             // 64 KB partials
    const int tid  = threadIdx.x;
    const int lane = tid & 63, w = tid >> 6;
    const int c = blockIdx.x;
    const u16* Ac = Vt2 + (size_t)c * CHELEM;  // A = V (rows d)
    const u16* Bc = Kt2 + (size_t)c * CHELEM;  // B = K (rows e)

    f32x4 acc[4][4] = {};                      // [dgrp][egrp]
    const int krow = lane & 15;
    const int kbase = w * 512 + (lane >> 4) * 8;

#pragma unroll 4
    for (int kt = 0; kt < 16; ++kt) {          // K-step 32 within slice
        const int k0 = kbase + kt * 32;
        bh8 a[4], b[4];
#pragma unroll
        for (int i = 0; i < 4; ++i) {
            a[i] = *(const bh8*)&Ac[(i * 16 + krow) * 2048 + k0];
            b[i] = *(const bh8*)&Bc[(i * 16 + krow) * 2048 + k0];
        }
#pragma unroll
        for (int i = 0; i < 4; ++i)
#pragma unroll
            for (int j = 0; j < 4; ++j)
                acc[i][j] = __builtin_amdgcn_mfma_f32_16x16x32_bf16(a[i], b[j], acc[i][j], 0, 0, 0);
    }

    // write per-wave partials: red[w][d*64+e]
#pragma unroll
    for (int i = 0; i < 4; ++i)
#pragma unroll
        for (int j = 0; j < 4; ++j)
#pragma unroll
            for (int r = 0; r < 4; ++r)
                red[w][(i * 16 + (lane >> 4) * 4 + r) * 64 + j * 16 + (lane & 15)] = acc[i][j][r];
    __syncthreads();

    // reduce 4 ways; strided so LDS reads are conflict-free and stores coalesce
    u16* Pc = Pb + c * 4096;
#pragma unroll
    for (int q = 0; q < 16; ++q) {
        const int idx = q * 256 + tid;
        float s = red[0][idx] + red[1][idx] + red[2][idx] + red[3][idx];
        Pc[idx] = f2bf(s * 0.125f);            // scale = DIM^-0.5
    }
}

// ---------------- K3: out_c = Q_c @ P_c^T  (K=64 per head, no LDS) ----------------
__global__ __launch_bounds__(256) void k3_out(
        const u16* __restrict__ Qb, const u16* __restrict__ Pb,
        float* __restrict__ outp) {
    const int tid = threadIdx.x;
    const int lane = tid & 63, w = tid >> 6;
    const int bb = blockIdx.x >> 6;          // 128 blocks: 64 row-blocks per bb
    const int ib = blockIdx.x & 63;
    const int i0 = ib * 32 + (w >> 1) * 16;  // row base within batch (A-frag rows)
    const int dbase = (w & 1) * 32;
    const int krow = lane & 15;
    const int koff = (lane >> 4) * 8;

    f32x4 acc[8][2] = {};                    // [head][nf]
#pragma unroll
    for (int h = 0; h < 8; ++h) {
        const int c = h * 2 + bb;
        const u16* Qc = Qb + (size_t)c * CHELEM;
        const u16* Pc = Pb + c * 4096;
#pragma unroll
        for (int ks = 0; ks < 2; ++ks) {
            bh8 a = *(const bh8*)&Qc[(i0 + krow) * 64 + ks * 32 + koff];
#pragma unroll
            for (int nf = 0; nf < 2; ++nf) {
                bh8 b = *(const bh8*)&Pc[(dbase + nf * 16 + krow) * 64 + ks * 32 + koff];
                acc[h][nf] = __builtin_amdgcn_mfma_f32_16x16x32_bf16(a, b, acc[h][nf], 0, 0, 0);
            }
        }
    }
    const int orow_base = bb * 2048 + ib * 32 + (w >> 1) * 16 + (lane >> 4) * 4;
#pragma unroll
    for (int nf = 0; nf < 2; ++nf) {
        const int d = dbase + nf * 16 + (lane & 15);
#pragma unroll
        for (int r = 0; r < 4; ++r) {
            f32x4 lo = {acc[0][nf][r], acc[1][nf][r], acc[2][nf][r], acc[3][nf][r]};
            f32x4 hi = {acc[4][nf][r], acc[5][nf][r], acc[6][nf][r], acc[7][nf][r]};
            float* dst = outp + (size_t)(orow_base + r) * 512 + d * 8;
            *(f32x4*)dst = lo;
            *(f32x4*)(dst + 4) = hi;
        }
    }
}

extern "C" void kernel_launch(void* const* d_in, const int* in_sizes, int n_in,
                              void* d_out, int out_size, void* d_ws, size_t ws_size,
                              hipStream_t stream) {
    const float* x  = (const float*)d_in[0];
    const float* Wq = (const float*)d_in[1];
    const float* bq = (const float*)d_in[2];
    const float* Wk = (const float*)d_in[3];
    const float* bk = (const float*)d_in[4];
    const float* Wv = (const float*)d_in[5];
    const float* bv = (const float*)d_in[6];
    float* outp = (float*)d_out;

    u16* xb = (u16*)d_ws;                 // 4096*512
    u16* Wb = xb + 2097152;               // 3*512*512
    u16* Qb = Wb + 786432;                // 4096*512 (straight)
    u16* Kb = Qb + 2097152;               // transposed chunks
    u16* Vb = Kb + 2097152;               // transposed chunks
    u16* Pb = Vb + 2097152;               // 16*64*64

    k0_convert<<<2816, 256, 0, stream>>>(x, Wq, Wk, Wv, xb, Wb);
    k1_qkv<<<384, 256, 0, stream>>>(xb, Wb, bq, bk, bv, Qb, Kb, Vb);
    k2_pmat<<<16, 256, 0, stream>>>(Kb, Vb, Pb);
    k3_out<<<128, 256, 0, stream>>>(Qb, Pb, outp);
}